// Round 1
// 297.967 us; speedup vs baseline: 1.2535x; 1.2535x over previous
//
#include <hip/hip_runtime.h>

#define N_NODES 20000
#define WCB_FLOATS (3*9*30*64)         // 51840 = repacked W_chem (wbody folded in)
#define NAB_FLOATS (N_NODES*32)        // 30 used per node, padded to 32

// ---------------------------------------------------------------------------
// Compile-time Wigner table (R6).
// R5 measured: main kernel 183 us but graph 373 us -> the init kernel's Job A
// (729 threads of divergent, dependency-chained fp64 factorial/CG/sqrt work,
// ~12 waves total) was ~190 us of pure serial latency. The Wigner table is a
// compile-time constant, so the identical algorithm is evaluated here as
// constexpr (fp64, same operation order; sqrt via converged Newton, <=1 ulp
// from device sqrt) and each coefficient is inlined into E() as a literal.
// ---------------------------------------------------------------------------
struct kx { double re, im; };

__host__ __device__ constexpr kx kmul(kx a, kx b){
  return { a.re*b.re - a.im*b.im, a.re*b.im + a.im*b.re };
}

__host__ __device__ constexpr double cfact(int n){
  double r = 1.0; for (int i = 2; i <= n; ++i) r *= (double)i; return r;
}

__host__ __device__ constexpr double csqrt(double x){
  if (x <= 0.0) return 0.0;
  double g = x > 1.0 ? x : 1.0;
  for (int i = 0; i < 64; ++i) g = 0.5*(g + x/g);   // converged fixed point
  return g;
}

__host__ __device__ constexpr double ccg(int j1,int m1,int j2,int m2,int j3,int m3){
  if (m3 != m1 + m2) return 0.0;
  int vmin = -j1 + j2 + m3;
  if (-j1 + m1 > vmin) vmin = -j1 + m1;
  if (vmin < 0) vmin = 0;
  int vmax = j2 + j3 + m1;
  if (j3 - j1 + j2 < vmax) vmax = j3 - j1 + j2;
  if (j3 + m3 < vmax) vmax = j3 + m3;
  double c = csqrt((double)(2*j3+1) *
      (cfact(j3+j1-j2)*cfact(j3-j1+j2)*cfact(j1+j2-j3)*cfact(j3+m3)*cfact(j3-m3)) /
      (cfact(j1+j2+j3+1)*cfact(j1-m1)*cfact(j1+m1)*cfact(j2-m2)*cfact(j2+m2)));
  double s = 0.0;
  for (int v = vmin; v <= vmax; ++v){
    double t = (cfact(j2+j3+m1-v)*cfact(j1-m1+v)) /
               (cfact(v)*cfact(j3-j1+j2-v)*cfact(j3+m3-v)*cfact(v+j1-j2-m3));
    s += ((v + j2 + m2) & 1) ? -t : t;
  }
  return c * s;
}

__host__ __device__ constexpr kx cq(int l, int r, int c){
  kx v = {0.0, 0.0};
  const double is2 = 0.70710678118654752440;
  const int m = r - l;
  if (m < 0){
    if (c == 2*l - r)      v = { is2, 0.0 };
    else if (c == r)       v = { 0.0, -is2 };
  } else if (m == 0){
    if (c == l)            v = { 1.0, 0.0 };
  } else {
    const double sg = (m & 1) ? -1.0 : 1.0;
    if (c == r)            v = { sg*is2, 0.0 };
    else if (c == 2*l - r) v = { 0.0, sg*is2 };
  }
  if (l == 1)      v = { v.im, -v.re };   // * (-i)
  else if (l == 2) v = { -v.re, -v.im };  // * (-i)^2 = -1
  return v;
}

// cw_entry(L,M,S) == R5's cw[(L*9+M)*9+S]: combined Wigner coeff with
// 1/sqrt(2l3+1) (su2_cg norm) and 1/sqrt(30)/sqrt(3) folded in.
__host__ __device__ constexpr double cw_entry(int L, int M, int S){
  const int l1 = (L==0)?0:((L<4)?1:2);
  const int l2 = (M==0)?0:((M<4)?1:2);
  const int l3 = (S==0)?0:((S<4)?1:2);
  const int a  = L - ((l1==0)?0:((l1==1)?1:4));
  const int b  = M - ((l2==0)?0:((l2==1)?1:4));
  const int cc = S - ((l3==0)?0:((l3==1)?1:4));
  const int lo = (l1 > l2) ? l1 - l2 : l2 - l1;
  if (!(l3 >= lo && l3 <= l1 + l2 && (((l1 + l2 + l3) & 1) == 0))) return 0.0;
  double ar = 0.0, ai = 0.0;
  for (int i = 0; i < 2*l1+1; ++i){
    kx q1 = cq(l1, i, a);
    if (q1.re == 0.0 && q1.im == 0.0) continue;
    for (int k = 0; k < 2*l2+1; ++k){
      kx q2 = cq(l2, k, b);
      if (q2.re == 0.0 && q2.im == 0.0) continue;
      kx q12 = kmul(q1, q2);
      for (int n = 0; n < 2*l3+1; ++n){
        kx q3 = cq(l3, n, cc);
        if (q3.re == 0.0 && q3.im == 0.0) continue;
        double cg = ccg(l1, i-l1, l2, k-l2, l3, n-l3);
        if (cg == 0.0) continue;
        kx q3c = { q3.re, -q3.im };
        kx term = kmul(q12, q3c);
        ar += term.re * cg;
        ai += term.im * cg;
      }
    }
  }
  const double w = ar / csqrt((double)(2*l3+1));
  return w * 0.10540925533894598;   // fold 1/sqrt(30)/sqrt(3)
}

// ---------------------------------------------------------------------------
// Init kernel, R6: only the runtime-dependent repacks remain (both streaming).
// Job B: repack W_chem -> wcB[b][d][k][c] = W_chem[k, d*192+3c+b] * wbody[b]
// Job C: scrambled chem rows, padded to 32 floats/node for scalar loads
// ---------------------------------------------------------------------------
__global__ void nn3b_init_kernel(const float* __restrict__ node_attr,
                                 const float* __restrict__ W_chem,
                                 const float* __restrict__ wbody,
                                 float* __restrict__ wcB,
                                 float* __restrict__ nab)
{
  const int t = blockIdx.x * 256 + threadIdx.x;

  if (t < WCB_FLOATS){
    const int c = t & 63;
    const int k = (t >> 6) % 30;
    const int d = (t / 1920) % 9;
    const int b = t / 17280;
    wcB[t] = W_chem[k*1728 + d*192 + 3*c + b] * wbody[b];
  }

  const int tc = t - WCB_FLOATS;
  if (tc >= 0 && tc < NAB_FLOATS){
    const int n = tc >> 5;
    const int k = tc & 31;
    float v = 0.0f;
    if (k < 30){
      const int i = 30*n + k;
      v = node_attr[(i % N_NODES)*10 + ((i / N_NODES) % 10)];
    }
    nab[tc] = v;
  }
}

// ---------------------------------------------------------------------------
// Main kernel: R5 structure unchanged (LDS-staged weights, 512 threads,
// 16 nodes/block, 2 nodes/wave, literal-index mem2reg discipline), except the
// Wigner coefficients are now compile-time literals (no cw pointer/loads).
// ---------------------------------------------------------------------------

// Stage chunk Q (3 dL slabs = 5760 floats = 1440 float4) of wcb_b into LDS.
#define STAGE(Q)                                                          \
  __syncthreads();                                                        \
  {                                                                       \
    const float4* src4 = (const float4*)(wcb_b + (Q)*5760);               \
    float4* dst4 = (float4*)ldsw;                                         \
    dst4[tid]       = src4[tid];                                          \
    dst4[tid + 512] = src4[tid + 512];                                    \
    if (tid < 416) dst4[tid + 1024] = src4[tid + 1024];                   \
  }                                                                       \
  __syncthreads();

// u for one dL from LDS slab SLAB (0..2): 2 half-chains per node.
#define UCOMP(SLAB)                                                       \
  {                                                                       \
    float a0=0.f, a1=0.f, b0=0.f, b1=0.f;                                 \
    const float* wp = ldsw + (SLAB)*1920 + c;                             \
    _Pragma("unroll")                                                     \
    for (int k = 0; k < 15; ++k){                                         \
      const float w0 = wp[k*64];                                          \
      const float w1 = wp[(k+15)*64];                                     \
      a0 = fmaf(nabA[k],    w0, a0);                                      \
      a1 = fmaf(nabA[k+15], w1, a1);                                      \
      b0 = fmaf(nabB[k],    w0, b0);                                      \
      b1 = fmaf(nabB[k+15], w1, b1);                                      \
    }                                                                     \
    uA = a0 + a1; uB = b0 + b1;                                           \
  }

// one tensor-product entry: o[S] += cw(DL,M,S) * u * v[M]
// cw(DL,M,S) is a compile-time literal — no memory access.
#define E(DL,M,S)                                                         \
  {                                                                       \
    constexpr float cc_ = (float)cw_entry(DL,M,S);                        \
    oA[S] = fmaf(cc_ * uA, vA[M], oA[S]);                                 \
    oB[S] = fmaf(cc_ * uB, vB[M], oB[S]);                                 \
  }

#define LD9(dst, p) { dst[0]=(p)[0]; dst[1]=(p)[1]; dst[2]=(p)[2];        \
                      dst[3]=(p)[3]; dst[4]=(p)[4]; dst[5]=(p)[5];        \
                      dst[6]=(p)[6]; dst[7]=(p)[7]; dst[8]=(p)[8]; }
#define ST9(p, src) { (p)[0]=src[0]; (p)[1]=src[1]; (p)[2]=src[2];        \
                      (p)[3]=src[3]; (p)[4]=src[4]; (p)[5]=src[5];        \
                      (p)[6]=src[6]; (p)[7]=src[7]; (p)[8]=src[8]; }

__global__ __launch_bounds__(512)
void nn3b_main_kernel(const float* __restrict__ nbody,
                      const float* __restrict__ wcB,
                      const float* __restrict__ nab,
                      float* __restrict__ out)
{
  __shared__ __align__(16) float ldsw[5760];   // 23,040 B: one 3-dL chunk

  const int tid = threadIdx.x;
  const int c   = tid & 63;
  const int g   = __builtin_amdgcn_readfirstlane((int)(tid >> 6)); // SGPR
  const int nA  = blockIdx.x * 16 + g * 2;   // this wave's node pair
  const int nB  = nA + 1;

  float oA[9] = {0,0,0,0,0,0,0,0,0};
  float oB[9] = {0,0,0,0,0,0,0,0,0};

  const float* nabA = nab + (size_t)nA * 32;
  const float* nabB = nab + (size_t)nB * 32;

  #pragma unroll 1   // keep body-order loop rolled: 3x smaller code
  for (int b = 0; b < 3; ++b){
    float vA[9], vB[9];
    {
      const float* pA = nbody + ((size_t)b*N_NODES + nA)*576 + c*9;
      const float* pB = nbody + ((size_t)b*N_NODES + nB)*576 + c*9;
      LD9(vA, pA);
      LD9(vB, pB);
    }
    const float* wcb_b = wcB + b*(9*30*64);
    float uA, uB;

    STAGE(0)                                    // dL 0,1,2
    UCOMP(0)
    E(0,0,0) E(0,1,1) E(0,2,2) E(0,3,3) E(0,4,4) E(0,5,5) E(0,6,6) E(0,7,7) E(0,8,8)
    UCOMP(1)
    E(1,0,1) E(1,1,0) E(1,3,4) E(1,2,5) E(1,1,6) E(1,1,8) E(1,4,3) E(1,5,2) E(1,6,1) E(1,8,1)
    UCOMP(2)
    E(2,0,2) E(2,2,0) E(2,1,5) E(2,3,7) E(2,2,6) E(2,5,1) E(2,7,3) E(2,6,2)

    STAGE(1)                                    // dL 3,4,5
    UCOMP(0)
    E(3,0,3) E(3,3,0) E(3,1,4) E(3,2,7) E(3,3,6) E(3,3,8) E(3,4,1) E(3,7,2) E(3,6,3) E(3,8,3)
    UCOMP(1)
    E(4,0,4) E(4,4,0) E(4,1,3) E(4,3,1) E(4,6,4) E(4,4,6) E(4,5,7) E(4,7,5)
    UCOMP(2)
    E(5,0,5) E(5,5,0) E(5,1,2) E(5,2,1) E(5,6,5) E(5,5,6) E(5,5,8) E(5,8,5) E(5,4,7) E(5,7,4)

    STAGE(2)                                    // dL 6,7,8
    UCOMP(0)
    E(6,0,6) E(6,6,0) E(6,1,1) E(6,2,2) E(6,3,3) E(6,6,6) E(6,5,5) E(6,7,7) E(6,4,4) E(6,8,8)
    UCOMP(1)
    E(7,0,7) E(7,7,0) E(7,2,3) E(7,3,2) E(7,6,7) E(7,7,6) E(7,7,8) E(7,8,7) E(7,4,5) E(7,5,4)
    UCOMP(2)
    E(8,0,8) E(8,8,0) E(8,1,1) E(8,3,3) E(8,6,8) E(8,8,6) E(8,5,5) E(8,7,7)
  }

  {
    float* pA = out + (size_t)nA*576 + c*9;
    float* pB = out + (size_t)nB*576 + c*9;
    ST9(pA, oA);
    ST9(pB, oB);
  }
}

extern "C" void kernel_launch(void* const* d_in, const int* in_sizes, int n_in,
                              void* d_out, int out_size, void* d_ws, size_t ws_size,
                              hipStream_t stream)
{
  const float* nbody     = (const float*)d_in[0];  // (3, 20000, 64, 9) f32
  const float* node_attr = (const float*)d_in[1];  // (20000, 10) f32
  const float* W_chem    = (const float*)d_in[2];  // (30, 1728) f32
  const float* wbody     = (const float*)d_in[3];  // (3, 1) f32
  float* out = (float*)d_out;                      // (20000, 64, 9) f32

  float* wcB = (float*)d_ws;          // 51840 f
  float* nab = wcB + WCB_FLOATS;      // 640000 f   (total ~2.65 MiB of ws)

  const int init_items  = WCB_FLOATS + NAB_FLOATS;
  const int init_blocks = (init_items + 255) / 256;
  nn3b_init_kernel<<<init_blocks, 256, 0, stream>>>(node_attr, W_chem, wbody, wcB, nab);

  nn3b_main_kernel<<<N_NODES/16, 512, 0, stream>>>(nbody, wcB, nab, out);
}

// Round 2
// 269.324 us; speedup vs baseline: 1.3868x; 1.1064x over previous
//
#include <hip/hip_runtime.h>

#define N_NODES 20000
#define WCB_FLOATS (3*9*30*64)         // 51840 = repacked W_chem (wbody folded in)
#define NAB_FLOATS (N_NODES*32)        // 30 used per node, padded to 32
#define U_FLOATS   (3*N_NODES*9*64)    // 34,560,000 = staged u[b][n][dL][c]

// ---------------------------------------------------------------------------
// Compile-time Wigner table (R6, unchanged): identical algorithm to the
// reference, evaluated as constexpr fp64; coefficients inlined as literals.
// ---------------------------------------------------------------------------
struct kx { double re, im; };

__host__ __device__ constexpr kx kmul(kx a, kx b){
  return { a.re*b.re - a.im*b.im, a.re*b.im + a.im*b.re };
}

__host__ __device__ constexpr double cfact(int n){
  double r = 1.0; for (int i = 2; i <= n; ++i) r *= (double)i; return r;
}

__host__ __device__ constexpr double csqrt(double x){
  if (x <= 0.0) return 0.0;
  double g = x > 1.0 ? x : 1.0;
  for (int i = 0; i < 64; ++i) g = 0.5*(g + x/g);   // converged fixed point
  return g;
}

__host__ __device__ constexpr double ccg(int j1,int m1,int j2,int m2,int j3,int m3){
  if (m3 != m1 + m2) return 0.0;
  int vmin = -j1 + j2 + m3;
  if (-j1 + m1 > vmin) vmin = -j1 + m1;
  if (vmin < 0) vmin = 0;
  int vmax = j2 + j3 + m1;
  if (j3 - j1 + j2 < vmax) vmax = j3 - j1 + j2;
  if (j3 + m3 < vmax) vmax = j3 + m3;
  double c = csqrt((double)(2*j3+1) *
      (cfact(j3+j1-j2)*cfact(j3-j1+j2)*cfact(j1+j2-j3)*cfact(j3+m3)*cfact(j3-m3)) /
      (cfact(j1+j2+j3+1)*cfact(j1-m1)*cfact(j1+m1)*cfact(j2-m2)*cfact(j2+m2)));
  double s = 0.0;
  for (int v = vmin; v <= vmax; ++v){
    double t = (cfact(j2+j3+m1-v)*cfact(j1-m1+v)) /
               (cfact(v)*cfact(j3-j1+j2-v)*cfact(j3+m3-v)*cfact(v+j1-j2-m3));
    s += ((v + j2 + m2) & 1) ? -t : t;
  }
  return c * s;
}

__host__ __device__ constexpr kx cq(int l, int r, int c){
  kx v = {0.0, 0.0};
  const double is2 = 0.70710678118654752440;
  const int m = r - l;
  if (m < 0){
    if (c == 2*l - r)      v = { is2, 0.0 };
    else if (c == r)       v = { 0.0, -is2 };
  } else if (m == 0){
    if (c == l)            v = { 1.0, 0.0 };
  } else {
    const double sg = (m & 1) ? -1.0 : 1.0;
    if (c == r)            v = { sg*is2, 0.0 };
    else if (c == 2*l - r) v = { 0.0, sg*is2 };
  }
  if (l == 1)      v = { v.im, -v.re };   // * (-i)
  else if (l == 2) v = { -v.re, -v.im };  // * (-i)^2 = -1
  return v;
}

__host__ __device__ constexpr double cw_entry(int L, int M, int S){
  const int l1 = (L==0)?0:((L<4)?1:2);
  const int l2 = (M==0)?0:((M<4)?1:2);
  const int l3 = (S==0)?0:((S<4)?1:2);
  const int a  = L - ((l1==0)?0:((l1==1)?1:4));
  const int b  = M - ((l2==0)?0:((l2==1)?1:4));
  const int cc = S - ((l3==0)?0:((l3==1)?1:4));
  const int lo = (l1 > l2) ? l1 - l2 : l2 - l1;
  if (!(l3 >= lo && l3 <= l1 + l2 && (((l1 + l2 + l3) & 1) == 0))) return 0.0;
  double ar = 0.0, ai = 0.0;
  for (int i = 0; i < 2*l1+1; ++i){
    kx q1 = cq(l1, i, a);
    if (q1.re == 0.0 && q1.im == 0.0) continue;
    for (int k = 0; k < 2*l2+1; ++k){
      kx q2 = cq(l2, k, b);
      if (q2.re == 0.0 && q2.im == 0.0) continue;
      kx q12 = kmul(q1, q2);
      for (int n = 0; n < 2*l3+1; ++n){
        kx q3 = cq(l3, n, cc);
        if (q3.re == 0.0 && q3.im == 0.0) continue;
        double cg = ccg(l1, i-l1, l2, k-l2, l3, n-l3);
        if (cg == 0.0) continue;
        kx q3c = { q3.re, -q3.im };
        kx term = kmul(q12, q3c);
        ar += term.re * cg;
        ai += term.im * cg;
      }
    }
  }
  const double w = ar / csqrt((double)(2*l3+1));
  return w * 0.10540925533894598;   // fold 1/sqrt(30)/sqrt(3)
}

// ---------------------------------------------------------------------------
// Init kernel (R6, unchanged): repack W_chem (wbody folded) + scrambled nab.
// ---------------------------------------------------------------------------
__global__ void nn3b_init_kernel(const float* __restrict__ node_attr,
                                 const float* __restrict__ W_chem,
                                 const float* __restrict__ wbody,
                                 float* __restrict__ wcB,
                                 float* __restrict__ nab)
{
  const int t = blockIdx.x * 256 + threadIdx.x;

  if (t < WCB_FLOATS){
    const int c = t & 63;
    const int k = (t >> 6) % 30;
    const int d = (t / 1920) % 9;
    const int b = t / 17280;
    wcB[t] = W_chem[k*1728 + d*192 + 3*c + b] * wbody[b];
  }

  const int tc = t - WCB_FLOATS;
  if (tc >= 0 && tc < NAB_FLOATS){
    const int n = tc >> 5;
    const int k = tc & 31;
    float v = 0.0f;
    if (k < 30){
      const int i = 30*n + k;
      v = node_attr[(i % N_NODES)*10 + ((i / N_NODES) % 10)];
    }
    nab[tc] = v;
  }
}

// ---------------------------------------------------------------------------
// R7 kernel 1: u-GEMM. u[b][n][dL][c] = sum_k nab[n][k] * wcB[b][dL][k][c].
// One wave owns (b, dL-triple) and 25 nodes: 90 weights live in VGPRs (lane=c,
// coalesced loads, reused 25x), nab rows are wave-uniform scalar loads, the
// two-chain k-reduction order matches R6's UCOMP exactly (bit-identical u).
// No LDS, no barriers; store-bound (~138 MB out).
// ---------------------------------------------------------------------------
__global__ __launch_bounds__(256)
void nn3b_u_kernel(const float* __restrict__ wcB,
                   const float* __restrict__ nab,
                   float* __restrict__ u_out)
{
  const int tid = threadIdx.x;
  const int c   = tid & 63;
  const int W   = __builtin_amdgcn_readfirstlane(blockIdx.x * 4 + (tid >> 6)); // 0..7199
  const int g   = W % 9;          // (b, dL-triple)
  const int b   = g / 3;
  const int s3  = g % 3;          // dL = s3*3 + {0,1,2}
  const int n0  = (W / 9) * 25;   // 800 strips x 25 nodes = 20000

  float w0[30], w1[30], w2[30];
  {
    const float* base = wcB + (size_t)((b*9 + s3*3)*30)*64 + c;
    #pragma unroll
    for (int k = 0; k < 30; ++k){
      w0[k] = base[(size_t)k*64];
      w1[k] = base[(size_t)(30 + k)*64];
      w2[k] = base[(size_t)(60 + k)*64];
    }
  }

  float* uo = u_out + ((size_t)(b*N_NODES + n0)*9 + s3*3)*64 + c;
  const float* na = nab + (size_t)n0*32;

  for (int i = 0; i < 25; ++i){
    float a0=0.f, a1=0.f, b0=0.f, b1=0.f, c0=0.f, c1=0.f;
    #pragma unroll
    for (int k = 0; k < 15; ++k){
      const float s0 = na[k];
      const float s1 = na[k + 15];
      a0 = fmaf(s0, w0[k],      a0);
      a1 = fmaf(s1, w0[k + 15], a1);
      b0 = fmaf(s0, w1[k],      b0);
      b1 = fmaf(s1, w1[k + 15], b1);
      c0 = fmaf(s0, w2[k],      c0);
      c1 = fmaf(s1, w2[k + 15], c1);
    }
    uo[0]   = a0 + a1;
    uo[64]  = b0 + b1;
    uo[128] = c0 + c1;
    uo += 9*64;
    na += 32;
  }
}

// ---------------------------------------------------------------------------
// R7 kernel 2: tensor-product contraction, pure streaming. One thread per
// (n,c): 27 coalesced u loads + 27 v loads + 83x3 fp32 path-FMAs (Wigner
// literals) + 9 stores. No LDS, no barriers, ~45 VGPR -> high occupancy.
// Same E-entry order and fp32 arithmetic as R6 (bit-identical output).
// ---------------------------------------------------------------------------
#define LD9(dst, p) { dst[0]=(p)[0]; dst[1]=(p)[1]; dst[2]=(p)[2];        \
                      dst[3]=(p)[3]; dst[4]=(p)[4]; dst[5]=(p)[5];        \
                      dst[6]=(p)[6]; dst[7]=(p)[7]; dst[8]=(p)[8]; }
#define ST9(p, src) { (p)[0]=src[0]; (p)[1]=src[1]; (p)[2]=src[2];        \
                      (p)[3]=src[3]; (p)[4]=src[4]; (p)[5]=src[5];        \
                      (p)[6]=src[6]; (p)[7]=src[7]; (p)[8]=src[8]; }

#define EC(DL,M,S)                                                        \
  {                                                                       \
    constexpr float cc_ = (float)cw_entry(DL,M,S);                        \
    o[S] = fmaf(cc_ * uu[DL], v[M], o[S]);                                \
  }

__global__ __launch_bounds__(256)
void nn3b_e_kernel(const float* __restrict__ nbody,
                   const float* __restrict__ u_in,
                   float* __restrict__ out)
{
  const int t = blockIdx.x * 256 + threadIdx.x;   // 1,280,000 threads
  const int c = t & 63;
  const int n = t >> 6;

  float o[9] = {0,0,0,0,0,0,0,0,0};

  #pragma unroll 1
  for (int b = 0; b < 3; ++b){
    float v[9];
    LD9(v, nbody + (size_t)(b*N_NODES + n)*576 + c*9);

    const float* pu = u_in + (size_t)(b*N_NODES + n)*576 + c;
    float uu[9];
    uu[0]=pu[0];   uu[1]=pu[64];  uu[2]=pu[128];
    uu[3]=pu[192]; uu[4]=pu[256]; uu[5]=pu[320];
    uu[6]=pu[384]; uu[7]=pu[448]; uu[8]=pu[512];

    EC(0,0,0) EC(0,1,1) EC(0,2,2) EC(0,3,3) EC(0,4,4) EC(0,5,5) EC(0,6,6) EC(0,7,7) EC(0,8,8)
    EC(1,0,1) EC(1,1,0) EC(1,3,4) EC(1,2,5) EC(1,1,6) EC(1,1,8) EC(1,4,3) EC(1,5,2) EC(1,6,1) EC(1,8,1)
    EC(2,0,2) EC(2,2,0) EC(2,1,5) EC(2,3,7) EC(2,2,6) EC(2,5,1) EC(2,7,3) EC(2,6,2)
    EC(3,0,3) EC(3,3,0) EC(3,1,4) EC(3,2,7) EC(3,3,6) EC(3,3,8) EC(3,4,1) EC(3,7,2) EC(3,6,3) EC(3,8,3)
    EC(4,0,4) EC(4,4,0) EC(4,1,3) EC(4,3,1) EC(4,6,4) EC(4,4,6) EC(4,5,7) EC(4,7,5)
    EC(5,0,5) EC(5,5,0) EC(5,1,2) EC(5,2,1) EC(5,6,5) EC(5,5,6) EC(5,5,8) EC(5,8,5) EC(5,4,7) EC(5,7,4)
    EC(6,0,6) EC(6,6,0) EC(6,1,1) EC(6,2,2) EC(6,3,3) EC(6,6,6) EC(6,5,5) EC(6,7,7) EC(6,4,4) EC(6,8,8)
    EC(7,0,7) EC(7,7,0) EC(7,2,3) EC(7,3,2) EC(7,6,7) EC(7,7,6) EC(7,7,8) EC(7,8,7) EC(7,4,5) EC(7,5,4)
    EC(8,0,8) EC(8,8,0) EC(8,1,1) EC(8,3,3) EC(8,6,8) EC(8,8,6) EC(8,5,5) EC(8,7,7)
  }

  ST9(out + (size_t)t*9, o);
}

// ---------------------------------------------------------------------------
// Fallback main kernel (R6, verbatim): used only if ws_size can't hold u.
// ---------------------------------------------------------------------------
#define STAGE(Q)                                                          \
  __syncthreads();                                                        \
  {                                                                       \
    const float4* src4 = (const float4*)(wcb_b + (Q)*5760);               \
    float4* dst4 = (float4*)ldsw;                                         \
    dst4[tid]       = src4[tid];                                          \
    dst4[tid + 512] = src4[tid + 512];                                    \
    if (tid < 416) dst4[tid + 1024] = src4[tid + 1024];                   \
  }                                                                       \
  __syncthreads();

#define UCOMP(SLAB)                                                       \
  {                                                                       \
    float a0=0.f, a1=0.f, b0=0.f, b1=0.f;                                 \
    const float* wp = ldsw + (SLAB)*1920 + c;                             \
    _Pragma("unroll")                                                     \
    for (int k = 0; k < 15; ++k){                                         \
      const float w0 = wp[k*64];                                          \
      const float w1 = wp[(k+15)*64];                                     \
      a0 = fmaf(nabA[k],    w0, a0);                                      \
      a1 = fmaf(nabA[k+15], w1, a1);                                      \
      b0 = fmaf(nabB[k],    w0, b0);                                      \
      b1 = fmaf(nabB[k+15], w1, b1);                                      \
    }                                                                     \
    uA = a0 + a1; uB = b0 + b1;                                           \
  }

#define E(DL,M,S)                                                         \
  {                                                                       \
    constexpr float cc_ = (float)cw_entry(DL,M,S);                        \
    oA[S] = fmaf(cc_ * uA, vA[M], oA[S]);                                 \
    oB[S] = fmaf(cc_ * uB, vB[M], oB[S]);                                 \
  }

__global__ __launch_bounds__(512)
void nn3b_main_kernel(const float* __restrict__ nbody,
                      const float* __restrict__ wcB,
                      const float* __restrict__ nab,
                      float* __restrict__ out)
{
  __shared__ __align__(16) float ldsw[5760];

  const int tid = threadIdx.x;
  const int c   = tid & 63;
  const int g   = __builtin_amdgcn_readfirstlane((int)(tid >> 6));
  const int nA  = blockIdx.x * 16 + g * 2;
  const int nB  = nA + 1;

  float oA[9] = {0,0,0,0,0,0,0,0,0};
  float oB[9] = {0,0,0,0,0,0,0,0,0};

  const float* nabA = nab + (size_t)nA * 32;
  const float* nabB = nab + (size_t)nB * 32;

  #pragma unroll 1
  for (int b = 0; b < 3; ++b){
    float vA[9], vB[9];
    {
      const float* pA = nbody + ((size_t)b*N_NODES + nA)*576 + c*9;
      const float* pB = nbody + ((size_t)b*N_NODES + nB)*576 + c*9;
      LD9(vA, pA);
      LD9(vB, pB);
    }
    const float* wcb_b = wcB + b*(9*30*64);
    float uA, uB;

    STAGE(0)
    UCOMP(0)
    E(0,0,0) E(0,1,1) E(0,2,2) E(0,3,3) E(0,4,4) E(0,5,5) E(0,6,6) E(0,7,7) E(0,8,8)
    UCOMP(1)
    E(1,0,1) E(1,1,0) E(1,3,4) E(1,2,5) E(1,1,6) E(1,1,8) E(1,4,3) E(1,5,2) E(1,6,1) E(1,8,1)
    UCOMP(2)
    E(2,0,2) E(2,2,0) E(2,1,5) E(2,3,7) E(2,2,6) E(2,5,1) E(2,7,3) E(2,6,2)

    STAGE(1)
    UCOMP(0)
    E(3,0,3) E(3,3,0) E(3,1,4) E(3,2,7) E(3,3,6) E(3,3,8) E(3,4,1) E(3,7,2) E(3,6,3) E(3,8,3)
    UCOMP(1)
    E(4,0,4) E(4,4,0) E(4,1,3) E(4,3,1) E(4,6,4) E(4,4,6) E(4,5,7) E(4,7,5)
    UCOMP(2)
    E(5,0,5) E(5,5,0) E(5,1,2) E(5,2,1) E(5,6,5) E(5,5,6) E(5,5,8) E(5,8,5) E(5,4,7) E(5,7,4)

    STAGE(2)
    UCOMP(0)
    E(6,0,6) E(6,6,0) E(6,1,1) E(6,2,2) E(6,3,3) E(6,6,6) E(6,5,5) E(6,7,7) E(6,4,4) E(6,8,8)
    UCOMP(1)
    E(7,0,7) E(7,7,0) E(7,2,3) E(7,3,2) E(7,6,7) E(7,7,6) E(7,7,8) E(7,8,7) E(7,4,5) E(7,5,4)
    UCOMP(2)
    E(8,0,8) E(8,8,0) E(8,1,1) E(8,3,3) E(8,6,8) E(8,8,6) E(8,5,5) E(8,7,7)
  }

  {
    float* pA = out + (size_t)nA*576 + c*9;
    float* pB = out + (size_t)nB*576 + c*9;
    ST9(pA, oA);
    ST9(pB, oB);
  }
}

extern "C" void kernel_launch(void* const* d_in, const int* in_sizes, int n_in,
                              void* d_out, int out_size, void* d_ws, size_t ws_size,
                              hipStream_t stream)
{
  const float* nbody     = (const float*)d_in[0];  // (3, 20000, 64, 9) f32
  const float* node_attr = (const float*)d_in[1];  // (20000, 10) f32
  const float* W_chem    = (const float*)d_in[2];  // (30, 1728) f32
  const float* wbody     = (const float*)d_in[3];  // (3, 1) f32
  float* out = (float*)d_out;                      // (20000, 64, 9) f32

  float* wcB = (float*)d_ws;          // 51840 f
  float* nab = wcB + WCB_FLOATS;      // 640000 f
  float* u   = nab + NAB_FLOATS;      // 34.56M f (only if ws permits)

  const int init_items  = WCB_FLOATS + NAB_FLOATS;
  const int init_blocks = (init_items + 255) / 256;
  nn3b_init_kernel<<<init_blocks, 256, 0, stream>>>(node_attr, W_chem, wbody, wcB, nab);

  const size_t need = ((size_t)WCB_FLOATS + NAB_FLOATS + U_FLOATS) * sizeof(float);
  if (ws_size >= need){
    // R7 path: barrier-free streaming pair.
    nn3b_u_kernel<<<1800, 256, 0, stream>>>(wcB, nab, u);      // 7200 waves
    nn3b_e_kernel<<<5000, 256, 0, stream>>>(nbody, u, out);    // 1 thread/(n,c)
  } else {
    // Fallback: R6 fused kernel (ws too small for u staging).
    nn3b_main_kernel<<<N_NODES/16, 512, 0, stream>>>(nbody, wcB, nab, out);
  }
}